// Round 2
// baseline (272.260 us; speedup 1.0000x reference)
//
#include <hip/hip_runtime.h>

// VectorCollapseEngine R4: single fully-fused kernel.
// h_final = A*h0 + sum_k w_k anchor_k, with (A,w) a function of 10 scalars:
//   {|h|^2, h.a0, h.a1, h.a2} (per row) + the 6 anchor Gram dots (row-indep).
// R2 (fused, one-lane recurrence between 2 barriers): ~98us addressable.
// R3 (3-kernel split): also ~98us — extra 128MB h0 re-read + 2 launch gaps
// ate what the parallel recurrence saved. R4 fixes both:
//  - Gram dots folded into pass 1 (anchors are already streaming through) ->
//    no setup kernel, no inter-kernel dependency.
//  - Recurrence runs REDUNDANTLY on all 256 threads from LDS partials:
//    no serial one-lane section, no second barrier, coef needs no broadcast.
//  - h stays in 16 VGPRs across the recurrence -> h0 read exactly once.
// HBM floor: 128MB read + 137MB write ~= 42us at 6.3 TB/s achievable.

constexpr int DIM = 4096;
constexpr int BATCH = 8192;
constexpr int NLAYERS = 6;
constexpr int TPB = 256;
constexpr int VPT = DIM / (TPB * 4);  // float4 chunks per thread = 4

constexpr size_t HOUT = (size_t)BATCH * DIM;            // h_final elems
constexpr size_t TRACE = (size_t)NLAYERS * BATCH * 3;   // per-trace elems
constexpr size_t OFF_ALIGN = HOUT;
constexpr size_t OFF_DIV   = HOUT + TRACE;
constexpr size_t OFF_TENS  = HOUT + 2 * TRACE;

__device__ __forceinline__ float wave_red(float v) {
#pragma unroll
  for (int off = 32; off > 0; off >>= 1) v += __shfl_down(v, off, 64);
  return v;  // lane 0 holds the wave sum
}

__global__ __launch_bounds__(TPB) void fused_kernel(
    const float* __restrict__ h0,
    const float* __restrict__ an0, const float* __restrict__ an1,
    const float* __restrict__ an2, float* __restrict__ out) {
  const int b = blockIdx.x;
  const int tid = threadIdx.x;
  const int lane = tid & 63, wv = tid >> 6;
  const float* hrow = h0 + (size_t)b * DIM;

  // ---- pass 1: h into registers; 10 dot-accumulators ----
  // r[0]=|h|^2  r[1..3]=h.a_k  r[4..6]=a_k.a_k  r[7]=a0.a1 r[8]=a0.a2 r[9]=a1.a2
  float4 hv[VPT];
  float r[10];
#pragma unroll
  for (int i = 0; i < 10; ++i) r[i] = 0.f;
#pragma unroll
  for (int j = 0; j < VPT; ++j) {
    const int idx = (tid + j * TPB) * 4;
    hv[j] = *(const float4*)(hrow + idx);
    const float4 x = *(const float4*)(an0 + idx);
    const float4 y = *(const float4*)(an1 + idx);
    const float4 z = *(const float4*)(an2 + idx);
    const float4 h = hv[j];
    r[0] += h.x*h.x + h.y*h.y + h.z*h.z + h.w*h.w;
    r[1] += h.x*x.x + h.y*x.y + h.z*x.z + h.w*x.w;
    r[2] += h.x*y.x + h.y*y.y + h.z*y.z + h.w*y.w;
    r[3] += h.x*z.x + h.y*z.y + h.z*z.z + h.w*z.w;
    r[4] += x.x*x.x + x.y*x.y + x.z*x.z + x.w*x.w;
    r[5] += y.x*y.x + y.y*y.y + y.z*y.z + y.w*y.w;
    r[6] += z.x*z.x + z.y*z.y + z.z*z.z + z.w*z.w;
    r[7] += x.x*y.x + x.y*y.y + x.z*y.z + x.w*y.w;
    r[8] += x.x*z.x + x.y*z.y + x.z*z.z + x.w*z.w;
    r[9] += y.x*z.x + y.y*z.y + y.z*z.z + y.w*z.w;
  }

  // ---- block reduction: 4 waves x 10 values ----
  __shared__ float lds[4][10];
#pragma unroll
  for (int i = 0; i < 10; ++i) r[i] = wave_red(r[i]);
  if (lane == 0) {
#pragma unroll
    for (int i = 0; i < 10; ++i) lds[wv][i] = r[i];
  }
  __syncthreads();

  // ---- recurrence: ALL threads, redundant & identical (no serial section).
  // LDS reads are same-address -> broadcast, no bank conflicts.
  float t[10];
#pragma unroll
  for (int i = 0; i < 10; ++i)
    t[i] = lds[0][i] + lds[1][i] + lds[2][i] + lds[3][i];

  const float n0 = fmaxf(sqrtf(t[4]), 1e-12f);
  const float n1 = fmaxf(sqrtf(t[5]), 1e-12f);
  const float n2 = fmaxf(sqrtf(t[6]), 1e-12f);
  float G[3][3];
  G[0][0] = t[4] / (n0 * n0);
  G[1][1] = t[5] / (n1 * n1);
  G[2][2] = t[6] / (n2 * n2);
  G[0][1] = G[1][0] = t[7] / (n0 * n1);
  G[0][2] = G[2][0] = t[8] / (n0 * n2);
  G[1][2] = G[2][1] = t[9] / (n1 * n2);

  const float str[3] = {0.1f, 0.1f, 0.05f};
  float s = t[0];
  float d[3] = {t[1] / n0, t[2] / n1, t[3] / n2};
  float A = 1.f;
  float B[3] = {0.f, 0.f, 0.f};

#pragma unroll
  for (int l = 0; l < NLAYERS; ++l) {
    const float hn = fmaxf(sqrtf(s), 1e-12f);
    float al[3], dv[3], c[3];
#pragma unroll
    for (int k = 0; k < 3; ++k) {
      al[k] = d[k] / hn;
      dv[k] = 1.f - al[k];
      const float rr = fmaxf(sqrtf(s - 2.f * d[k] + G[k][k]), 1e-12f);
      c[k] = str[k] * dv[k] / rr;
    }
    if (tid == 0) {
#pragma unroll
      for (int k = 0; k < 3; ++k) {
        const size_t o = (size_t)l * (BATCH * 3) + (size_t)b * 3 + k;
        out[OFF_ALIGN + o] = al[k];
        out[OFF_DIV + o]   = dv[k];
        out[OFF_TENS + o]  = fmaxf(dv[k], 0.f);
      }
    }
    const float a = 1.f - (c[0] + c[1] + c[2]);
    float dn[3];
#pragma unroll
    for (int j = 0; j < 3; ++j)
      dn[j] = a * d[j] + c[0] * G[0][j] + c[1] * G[1][j] + c[2] * G[2][j];
    float sn = a * a * s + 2.f * a * (c[0]*d[0] + c[1]*d[1] + c[2]*d[2]);
#pragma unroll
    for (int k = 0; k < 3; ++k)
#pragma unroll
      for (int j = 0; j < 3; ++j) sn += c[k] * c[j] * G[k][j];
    A = a * A;
#pragma unroll
    for (int j = 0; j < 3; ++j) B[j] = a * B[j] + c[j];
    s = sn;
#pragma unroll
    for (int j = 0; j < 3; ++j) d[j] = dn[j];
    const float hn2 = sqrtf(s);
    if (hn2 > 10.0f) {
      const float sc = 10.0f / (hn2 + 1e-8f);
      A *= sc;
#pragma unroll
      for (int j = 0; j < 3; ++j) { B[j] *= sc; d[j] *= sc; }
      s *= sc * sc;
    }
  }
  const float w0 = B[0] / n0, w1 = B[1] / n1, w2 = B[2] / n2;

  // ---- pass 2: h from registers; anchors re-read (L1/L2-hot, 48KB) ----
  float* orow = out + (size_t)b * DIM;
#pragma unroll
  for (int j = 0; j < VPT; ++j) {
    const int idx = (tid + j * TPB) * 4;
    const float4 x = *(const float4*)(an0 + idx);
    const float4 y = *(const float4*)(an1 + idx);
    const float4 z = *(const float4*)(an2 + idx);
    const float4 h = hv[j];
    float4 o;
    o.x = A * h.x + w0 * x.x + w1 * y.x + w2 * z.x;
    o.y = A * h.y + w0 * x.y + w1 * y.y + w2 * z.y;
    o.z = A * h.z + w0 * x.z + w1 * y.z + w2 * z.z;
    o.w = A * h.w + w0 * x.w + w1 * y.w + w2 * z.w;
    *(float4*)(orow + idx) = o;
  }
}

extern "C" void kernel_launch(void* const* d_in, const int* in_sizes, int n_in,
                              void* d_out, int out_size, void* d_ws, size_t ws_size,
                              hipStream_t stream) {
  const float* h0  = (const float*)d_in[0];
  const float* an0 = (const float*)d_in[1];
  const float* an1 = (const float*)d_in[2];
  const float* an2 = (const float*)d_in[3];
  float* out = (float*)d_out;
  (void)d_ws; (void)ws_size;
  fused_kernel<<<BATCH, TPB, 0, stream>>>(h0, an0, an1, an2, out);
}

// Round 4
// 259.736 us; speedup vs baseline: 1.0482x; 1.0482x over previous
//
#include <hip/hip_runtime.h>

// VectorCollapseEngine R5 (resubmit — prior round hit infra failure, never ran).
// R4 counters: fused=121us, VALUBusy=88.6%, HBM=21% -> VALU-issue-bound.
// Static count said ~75% of slots were (a) anchor Gram recomputed per block
// (96 FMA/thread, identical across 8192 blocks) and (b) the 6-layer
// recurrence compiled with IEEE div (10 inst) / sqrt (8 inst) sequences.
// R5: (1) Gram hoisted to a 1-block setup kernel (stores 1/n pre-inverted);
//     (2) recurrence rewritten division-free with native v_rsq/v_rcp/v_sqrt
//         (~1e-7 rel err vs measured absmax 2e-3 -> noise);
//     (3) block reduce shrinks 10 -> 4 values.
// h stays in VGPRs (read h0 once); anchors re-read in pass 2 (L2-hot) to
// keep VGPR~52 / 8 waves-SIMD occupancy.
// Floor: ~66MB L3-miss fetch + 137MB write ~= 32us.

constexpr int DIM = 4096;
constexpr int BATCH = 8192;
constexpr int NLAYERS = 6;
constexpr int TPB = 256;
constexpr int VPT = DIM / (TPB * 4);  // float4 chunks per thread = 4

constexpr size_t HOUT = (size_t)BATCH * DIM;            // h_final elems
constexpr size_t TRACE = (size_t)NLAYERS * BATCH * 3;   // per-trace elems
constexpr size_t OFF_ALIGN = HOUT;
constexpr size_t OFF_DIV   = HOUT + TRACE;
constexpr size_t OFF_TENS  = HOUT + 2 * TRACE;

// g_gram: [rn0, rn1, rn2, G00, G11, G22, G01, G02, G12]  (rn = 1/|anchor|)
__device__ float g_gram[12];

__device__ __forceinline__ float frcp(float x) { return __builtin_amdgcn_rcpf(x); }
__device__ __forceinline__ float frsq(float x) { return __builtin_amdgcn_rsqf(x); }
__device__ __forceinline__ float fsq(float x)  { return __builtin_amdgcn_sqrtf(x); }

__device__ __forceinline__ float wave_red(float v) {
#pragma unroll
  for (int off = 32; off > 0; off >>= 1) v += __shfl_down(v, off, 64);
  return v;  // lane 0 holds the wave sum
}

// ---- setup: anchor Gram / inverse norms (1 block; precise math, cold) ----
__global__ __launch_bounds__(TPB) void gram_kernel(
    const float* __restrict__ an0, const float* __restrict__ an1,
    const float* __restrict__ an2) {
  const int tid = threadIdx.x;
  float r[6];
#pragma unroll
  for (int i = 0; i < 6; ++i) r[i] = 0.f;
#pragma unroll
  for (int j = 0; j < VPT; ++j) {
    const int idx = (tid + j * TPB) * 4;
    const float4 x = *(const float4*)(an0 + idx);
    const float4 y = *(const float4*)(an1 + idx);
    const float4 z = *(const float4*)(an2 + idx);
    r[0] += x.x*x.x + x.y*x.y + x.z*x.z + x.w*x.w;
    r[1] += y.x*y.x + y.y*y.y + y.z*y.z + y.w*y.w;
    r[2] += z.x*z.x + z.y*z.y + z.z*z.z + z.w*z.w;
    r[3] += x.x*y.x + x.y*y.y + x.z*y.z + x.w*y.w;
    r[4] += x.x*z.x + x.y*z.y + x.z*z.z + x.w*z.w;
    r[5] += y.x*z.x + y.y*z.y + y.z*z.z + y.w*z.w;
  }
  __shared__ float lds[4][6];
  const int lane = tid & 63, wv = tid >> 6;
#pragma unroll
  for (int i = 0; i < 6; ++i) r[i] = wave_red(r[i]);
  if (lane == 0) {
#pragma unroll
    for (int i = 0; i < 6; ++i) lds[wv][i] = r[i];
  }
  __syncthreads();
  if (tid == 0) {
#pragma unroll
    for (int i = 0; i < 6; ++i)
      r[i] = lds[0][i] + lds[1][i] + lds[2][i] + lds[3][i];
    const float n0 = fmaxf(sqrtf(r[0]), 1e-12f);
    const float n1 = fmaxf(sqrtf(r[1]), 1e-12f);
    const float n2 = fmaxf(sqrtf(r[2]), 1e-12f);
    g_gram[0] = 1.f / n0;
    g_gram[1] = 1.f / n1;
    g_gram[2] = 1.f / n2;
    g_gram[3] = r[0] / (n0 * n0);
    g_gram[4] = r[1] / (n1 * n1);
    g_gram[5] = r[2] / (n2 * n2);
    g_gram[6] = r[3] / (n0 * n1);
    g_gram[7] = r[4] / (n0 * n2);
    g_gram[8] = r[5] / (n1 * n2);
  }
}

__global__ __launch_bounds__(TPB) void fused_kernel(
    const float* __restrict__ h0,
    const float* __restrict__ an0, const float* __restrict__ an1,
    const float* __restrict__ an2, float* __restrict__ out) {
  const int b = blockIdx.x;
  const int tid = threadIdx.x;
  const int lane = tid & 63, wv = tid >> 6;
  const float* hrow = h0 + (size_t)b * DIM;

  // ---- pass 1: h into registers; 4 dot accumulators (Gram hoisted) ----
  float4 hv[VPT];
  float r0 = 0.f, r1 = 0.f, r2 = 0.f, r3 = 0.f;
#pragma unroll
  for (int j = 0; j < VPT; ++j) {
    const int idx = (tid + j * TPB) * 4;
    hv[j] = *(const float4*)(hrow + idx);
    const float4 x = *(const float4*)(an0 + idx);
    const float4 y = *(const float4*)(an1 + idx);
    const float4 z = *(const float4*)(an2 + idx);
    const float4 h = hv[j];
    r0 += h.x*h.x + h.y*h.y + h.z*h.z + h.w*h.w;
    r1 += h.x*x.x + h.y*x.y + h.z*x.z + h.w*x.w;
    r2 += h.x*y.x + h.y*y.y + h.z*y.z + h.w*y.w;
    r3 += h.x*z.x + h.y*z.y + h.z*z.z + h.w*z.w;
  }

  // ---- block reduction: 4 waves x 4 values ----
  __shared__ float lds[4][4];
  r0 = wave_red(r0); r1 = wave_red(r1); r2 = wave_red(r2); r3 = wave_red(r3);
  if (lane == 0) {
    lds[wv][0] = r0; lds[wv][1] = r1; lds[wv][2] = r2; lds[wv][3] = r3;
  }
  __syncthreads();

  // ---- recurrence: all threads redundant (wave-balanced, no 2nd barrier);
  //      division-free via native v_rsq / v_rcp (rel err ~1e-7). ----
  float s  = lds[0][0] + lds[1][0] + lds[2][0] + lds[3][0];
  float d0 = lds[0][1] + lds[1][1] + lds[2][1] + lds[3][1];
  float d1 = lds[0][2] + lds[1][2] + lds[2][2] + lds[3][2];
  float d2 = lds[0][3] + lds[1][3] + lds[2][3] + lds[3][3];

  const float rn0 = g_gram[0], rn1 = g_gram[1], rn2 = g_gram[2];
  const float G00 = g_gram[3], G11 = g_gram[4], G22 = g_gram[5];
  const float G01 = g_gram[6], G02 = g_gram[7], G12 = g_gram[8];
  d0 *= rn0; d1 *= rn1; d2 *= rn2;

  float A = 1.f, B0 = 0.f, B1 = 0.f, B2 = 0.f;
  float* tr_al = out + OFF_ALIGN + (size_t)b * 3;
  float* tr_dv = out + OFF_DIV   + (size_t)b * 3;
  float* tr_tn = out + OFF_TENS  + (size_t)b * 3;

#pragma unroll
  for (int l = 0; l < NLAYERS; ++l) {
    const float rhn = frsq(fmaxf(s, 1e-24f));        // 1/max(|h|,1e-12)
    const float al0 = d0 * rhn, al1 = d1 * rhn, al2 = d2 * rhn;
    const float dv0 = 1.f - al0, dv1 = 1.f - al1, dv2 = 1.f - al2;
    const float rr0 = frsq(fmaxf(s - 2.f*d0 + G00, 1e-24f));
    const float rr1 = frsq(fmaxf(s - 2.f*d1 + G11, 1e-24f));
    const float rr2 = frsq(fmaxf(s - 2.f*d2 + G22, 1e-24f));
    const float c0 = 0.10f * dv0 * rr0;
    const float c1 = 0.10f * dv1 * rr1;
    const float c2 = 0.05f * dv2 * rr2;
    if (tid == 0) {
      const size_t o = (size_t)l * (BATCH * 3);
      tr_al[o+0] = al0; tr_al[o+1] = al1; tr_al[o+2] = al2;
      tr_dv[o+0] = dv0; tr_dv[o+1] = dv1; tr_dv[o+2] = dv2;
      tr_tn[o+0] = fmaxf(dv0, 0.f); tr_tn[o+1] = fmaxf(dv1, 0.f);
      tr_tn[o+2] = fmaxf(dv2, 0.f);
    }
    const float a = 1.f - (c0 + c1 + c2);
    const float dn0 = a*d0 + c0*G00 + c1*G01 + c2*G02;
    const float dn1 = a*d1 + c0*G01 + c1*G11 + c2*G12;
    const float dn2 = a*d2 + c0*G02 + c1*G12 + c2*G22;
    float sn = a*a*s + 2.f*a*(c0*d0 + c1*d1 + c2*d2)
             + c0*c0*G00 + c1*c1*G11 + c2*c2*G22
             + 2.f*(c0*c1*G01 + c0*c2*G02 + c1*c2*G12);
    A = a * A;
    B0 = a*B0 + c0; B1 = a*B1 + c1; B2 = a*B2 + c2;
    s = sn; d0 = dn0; d1 = dn1; d2 = dn2;
    const float hn2 = fsq(s);
    if (hn2 > 10.0f) {                                // uniform branch
      const float sc = 10.0f * frcp(hn2 + 1e-8f);
      A *= sc; B0 *= sc; B1 *= sc; B2 *= sc;
      d0 *= sc; d1 *= sc; d2 *= sc;
      s *= sc * sc;
    }
  }
  const float w0 = B0 * rn0, w1 = B1 * rn1, w2 = B2 * rn2;

  // ---- pass 2: h from registers; anchors re-read (L2-hot, 48KB) ----
  float* orow = out + (size_t)b * DIM;
#pragma unroll
  for (int j = 0; j < VPT; ++j) {
    const int idx = (tid + j * TPB) * 4;
    const float4 x = *(const float4*)(an0 + idx);
    const float4 y = *(const float4*)(an1 + idx);
    const float4 z = *(const float4*)(an2 + idx);
    const float4 h = hv[j];
    float4 o;
    o.x = A * h.x + w0 * x.x + w1 * y.x + w2 * z.x;
    o.y = A * h.y + w0 * x.y + w1 * y.y + w2 * z.y;
    o.z = A * h.z + w0 * x.z + w1 * y.z + w2 * z.z;
    o.w = A * h.w + w0 * x.w + w1 * y.w + w2 * z.w;
    *(float4*)(orow + idx) = o;
  }
}

extern "C" void kernel_launch(void* const* d_in, const int* in_sizes, int n_in,
                              void* d_out, int out_size, void* d_ws, size_t ws_size,
                              hipStream_t stream) {
  const float* h0  = (const float*)d_in[0];
  const float* an0 = (const float*)d_in[1];
  const float* an1 = (const float*)d_in[2];
  const float* an2 = (const float*)d_in[3];
  float* out = (float*)d_out;
  (void)d_ws; (void)ws_size;
  gram_kernel<<<1, TPB, 0, stream>>>(an0, an1, an2);
  fused_kernel<<<BATCH, TPB, 0, stream>>>(h0, an0, an1, an2, out);
}

// Round 5
// 253.485 us; speedup vs baseline: 1.0741x; 1.0247x over previous
//
#include <hip/hip_runtime.h>

// VectorCollapseEngine R6: wave-per-row, barrier-free.
// R5 counters: fused=96.7us, VALUBusy=37%, HBM=27% -> BOTH pipes idle =
// latency/phase-convoy bound. All blocks/CU ran the same phases in lockstep
// (barrier-aligned): memory phase with VALU idle, then VALU phase with
// memory idle. R6 gives each WAVE one full row:
//   - lane l owns 16 float4s of the row (h in 64 VGPRs, read h0 once);
//   - dots reduced with shfl_xor butterfly (all lanes get sum) -> NO LDS,
//     NO __syncthreads, waves never sync -> phases drift & overlap;
//   - recurrence redundant per-lane but now on 8192 waves (was 32768);
//   - pass 2: anchors re-read (L2-hot), h from registers.
// gram stays hoisted (R5). Floor: ~66MB L3-miss fetch + 137MB write ~= 32us.

constexpr int DIM = 4096;
constexpr int BATCH = 8192;
constexpr int NLAYERS = 6;
constexpr int TPB = 256;
constexpr int WPB = TPB / 64;             // waves per block = 4
constexpr int GRID = BATCH / WPB;         // 2048 blocks, 1 row per wave
constexpr int FPW = DIM / (64 * 4);       // float4 chunks per lane = 16

constexpr size_t HOUT = (size_t)BATCH * DIM;            // h_final elems
constexpr size_t TRACE = (size_t)NLAYERS * BATCH * 3;   // per-trace elems
constexpr size_t OFF_ALIGN = HOUT;
constexpr size_t OFF_DIV   = HOUT + TRACE;
constexpr size_t OFF_TENS  = HOUT + 2 * TRACE;

// g_gram: [rn0, rn1, rn2, G00, G11, G22, G01, G02, G12]  (rn = 1/|anchor|)
__device__ float g_gram[12];

__device__ __forceinline__ float frcp(float x) { return __builtin_amdgcn_rcpf(x); }
__device__ __forceinline__ float frsq(float x) { return __builtin_amdgcn_rsqf(x); }
__device__ __forceinline__ float fsq(float x)  { return __builtin_amdgcn_sqrtf(x); }

__device__ __forceinline__ float wave_red(float v) {   // lane-0 sum (setup only)
#pragma unroll
  for (int off = 32; off > 0; off >>= 1) v += __shfl_down(v, off, 64);
  return v;
}

__device__ __forceinline__ float wave_allred(float v) { // all lanes get sum
#pragma unroll
  for (int off = 32; off > 0; off >>= 1) v += __shfl_xor(v, off, 64);
  return v;
}

// ---- setup: anchor Gram / inverse norms (1 block; precise math, cold) ----
__global__ __launch_bounds__(TPB) void gram_kernel(
    const float* __restrict__ an0, const float* __restrict__ an1,
    const float* __restrict__ an2) {
  const int tid = threadIdx.x;
  float r[6];
#pragma unroll
  for (int i = 0; i < 6; ++i) r[i] = 0.f;
#pragma unroll
  for (int j = 0; j < DIM / (TPB * 4); ++j) {
    const int idx = (tid + j * TPB) * 4;
    const float4 x = *(const float4*)(an0 + idx);
    const float4 y = *(const float4*)(an1 + idx);
    const float4 z = *(const float4*)(an2 + idx);
    r[0] += x.x*x.x + x.y*x.y + x.z*x.z + x.w*x.w;
    r[1] += y.x*y.x + y.y*y.y + y.z*y.z + y.w*y.w;
    r[2] += z.x*z.x + z.y*z.y + z.z*z.z + z.w*z.w;
    r[3] += x.x*y.x + x.y*y.y + x.z*y.z + x.w*y.w;
    r[4] += x.x*z.x + x.y*z.y + x.z*z.z + x.w*z.w;
    r[5] += y.x*z.x + y.y*z.y + y.z*z.z + y.w*z.w;
  }
  __shared__ float lds[4][6];
  const int lane = tid & 63, wv = tid >> 6;
#pragma unroll
  for (int i = 0; i < 6; ++i) r[i] = wave_red(r[i]);
  if (lane == 0) {
#pragma unroll
    for (int i = 0; i < 6; ++i) lds[wv][i] = r[i];
  }
  __syncthreads();
  if (tid == 0) {
#pragma unroll
    for (int i = 0; i < 6; ++i)
      r[i] = lds[0][i] + lds[1][i] + lds[2][i] + lds[3][i];
    const float n0 = fmaxf(sqrtf(r[0]), 1e-12f);
    const float n1 = fmaxf(sqrtf(r[1]), 1e-12f);
    const float n2 = fmaxf(sqrtf(r[2]), 1e-12f);
    g_gram[0] = 1.f / n0;
    g_gram[1] = 1.f / n1;
    g_gram[2] = 1.f / n2;
    g_gram[3] = r[0] / (n0 * n0);
    g_gram[4] = r[1] / (n1 * n1);
    g_gram[5] = r[2] / (n2 * n2);
    g_gram[6] = r[3] / (n0 * n1);
    g_gram[7] = r[4] / (n0 * n2);
    g_gram[8] = r[5] / (n1 * n2);
  }
}

__global__ __launch_bounds__(TPB) void fused_kernel(
    const float* __restrict__ h0,
    const float* __restrict__ an0, const float* __restrict__ an1,
    const float* __restrict__ an2, float* __restrict__ out) {
  const int lane = threadIdx.x & 63;
  const int wv = threadIdx.x >> 6;
  const int b = blockIdx.x * WPB + wv;            // this wave's row
  const float* hrow = h0 + (size_t)b * DIM;

  // ---- pass 1: whole row into 64 VGPRs; 4 dot accumulators ----
  float4 hv[FPW];
  float r0 = 0.f, r1 = 0.f, r2 = 0.f, r3 = 0.f;
#pragma unroll
  for (int j = 0; j < FPW; ++j) {
    const int idx = (j * 64 + lane) * 4;          // coalesced per wave
    hv[j] = *(const float4*)(hrow + idx);
    const float4 x = *(const float4*)(an0 + idx);
    const float4 y = *(const float4*)(an1 + idx);
    const float4 z = *(const float4*)(an2 + idx);
    const float4 h = hv[j];
    r0 += h.x*h.x + h.y*h.y + h.z*h.z + h.w*h.w;
    r1 += h.x*x.x + h.y*x.y + h.z*x.z + h.w*x.w;
    r2 += h.x*y.x + h.y*y.y + h.z*y.z + h.w*y.w;
    r3 += h.x*z.x + h.y*z.y + h.z*z.z + h.w*z.w;
  }

  // ---- wave-local butterfly reduce: all lanes hold the sums; no LDS ----
  float s  = wave_allred(r0);
  float d0 = wave_allred(r1);
  float d1 = wave_allred(r2);
  float d2 = wave_allred(r3);

  const float rn0 = g_gram[0], rn1 = g_gram[1], rn2 = g_gram[2];
  const float G00 = g_gram[3], G11 = g_gram[4], G22 = g_gram[5];
  const float G01 = g_gram[6], G02 = g_gram[7], G12 = g_gram[8];
  d0 *= rn0; d1 *= rn1; d2 *= rn2;

  float A = 1.f, B0 = 0.f, B1 = 0.f, B2 = 0.f;
  float* tr_al = out + OFF_ALIGN + (size_t)b * 3;
  float* tr_dv = out + OFF_DIV   + (size_t)b * 3;
  float* tr_tn = out + OFF_TENS  + (size_t)b * 3;

  // ---- recurrence: redundant per-lane (8192 waves total, was 32768);
  //      division-free via native v_rsq / v_rcp (rel err ~1e-7). ----
#pragma unroll
  for (int l = 0; l < NLAYERS; ++l) {
    const float rhn = frsq(fmaxf(s, 1e-24f));
    const float al0 = d0 * rhn, al1 = d1 * rhn, al2 = d2 * rhn;
    const float dv0 = 1.f - al0, dv1 = 1.f - al1, dv2 = 1.f - al2;
    const float rr0 = frsq(fmaxf(s - 2.f*d0 + G00, 1e-24f));
    const float rr1 = frsq(fmaxf(s - 2.f*d1 + G11, 1e-24f));
    const float rr2 = frsq(fmaxf(s - 2.f*d2 + G22, 1e-24f));
    const float c0 = 0.10f * dv0 * rr0;
    const float c1 = 0.10f * dv1 * rr1;
    const float c2 = 0.05f * dv2 * rr2;
    if (lane == 0) {
      const size_t o = (size_t)l * (BATCH * 3);
      tr_al[o+0] = al0; tr_al[o+1] = al1; tr_al[o+2] = al2;
      tr_dv[o+0] = dv0; tr_dv[o+1] = dv1; tr_dv[o+2] = dv2;
      tr_tn[o+0] = fmaxf(dv0, 0.f); tr_tn[o+1] = fmaxf(dv1, 0.f);
      tr_tn[o+2] = fmaxf(dv2, 0.f);
    }
    const float a = 1.f - (c0 + c1 + c2);
    const float dn0 = a*d0 + c0*G00 + c1*G01 + c2*G02;
    const float dn1 = a*d1 + c0*G01 + c1*G11 + c2*G12;
    const float dn2 = a*d2 + c0*G02 + c1*G12 + c2*G22;
    float sn = a*a*s + 2.f*a*(c0*d0 + c1*d1 + c2*d2)
             + c0*c0*G00 + c1*c1*G11 + c2*c2*G22
             + 2.f*(c0*c1*G01 + c0*c2*G02 + c1*c2*G12);
    A = a * A;
    B0 = a*B0 + c0; B1 = a*B1 + c1; B2 = a*B2 + c2;
    s = sn; d0 = dn0; d1 = dn1; d2 = dn2;
    const float hn2 = fsq(s);
    if (hn2 > 10.0f) {                              // wave-uniform branch
      const float sc = 10.0f * frcp(hn2 + 1e-8f);
      A *= sc; B0 *= sc; B1 *= sc; B2 *= sc;
      d0 *= sc; d1 *= sc; d2 *= sc;
      s *= sc * sc;
    }
  }
  const float w0 = B0 * rn0, w1 = B1 * rn1, w2 = B2 * rn2;

  // ---- pass 2: h from registers; anchors re-read (L2-hot, 48KB) ----
  float* orow = out + (size_t)b * DIM;
#pragma unroll
  for (int j = 0; j < FPW; ++j) {
    const int idx = (j * 64 + lane) * 4;
    const float4 x = *(const float4*)(an0 + idx);
    const float4 y = *(const float4*)(an1 + idx);
    const float4 z = *(const float4*)(an2 + idx);
    const float4 h = hv[j];
    float4 o;
    o.x = A * h.x + w0 * x.x + w1 * y.x + w2 * z.x;
    o.y = A * h.y + w0 * x.y + w1 * y.y + w2 * z.y;
    o.z = A * h.z + w0 * x.z + w1 * y.z + w2 * z.z;
    o.w = A * h.w + w0 * x.w + w1 * y.w + w2 * z.w;
    *(float4*)(orow + idx) = o;
  }
}

extern "C" void kernel_launch(void* const* d_in, const int* in_sizes, int n_in,
                              void* d_out, int out_size, void* d_ws, size_t ws_size,
                              hipStream_t stream) {
  const float* h0  = (const float*)d_in[0];
  const float* an0 = (const float*)d_in[1];
  const float* an1 = (const float*)d_in[2];
  const float* an2 = (const float*)d_in[3];
  float* out = (float*)d_out;
  (void)d_ws; (void)ws_size;
  gram_kernel<<<1, TPB, 0, stream>>>(an0, an1, an2);
  fused_kernel<<<GRID, TPB, 0, stream>>>(h0, an0, an1, an2, out);
}

// Round 6
// 250.216 us; speedup vs baseline: 1.0881x; 1.0131x over previous
//
#include <hip/hip_runtime.h>

// VectorCollapseEngine R7: R6 + LDS anchor staging + 512-thread blocks.
// R6 counters: fused=90us, VALUBusy=18%, HBM=28%, Occ=17.6% -> memory-path
// bound: (a) every wave re-read the 48KB anchors TWICE from L2 (786MB of
// L2 traffic vs 204MB mandatory HBM; anchors thrash the 32KB L1), and
// (b) VGPR=128 + small effective residency left too few loads in flight.
// R7: block stages anchors into LDS once (48KB, one barrier, read-only
// after), both passes read anchors via ds_read_b128 (conflict-free);
// TPB=512 amortizes staging 8x; 2 blocks/CU = 96KB LDS, 16 waves/CU.
// Global anchor traffic 786MB -> 98MB; vector-global path 1.05GB -> 365MB.
// h stays in 64 VGPRs (h0 read exactly once); waves stay barrier-free
// after the single staging barrier. Floor ~32us (66MB miss + 137MB write).

constexpr int DIM = 4096;
constexpr int BATCH = 8192;
constexpr int NLAYERS = 6;
constexpr int TPB = 512;                  // 8 waves per block
constexpr int WPB = TPB / 64;             // waves per block = 8
constexpr int GRID = BATCH / WPB;         // 1024 blocks, 1 row per wave
constexpr int FPW = DIM / (64 * 4);       // float4 chunks per lane = 16
constexpr int GTPB = 256;                 // gram kernel block size

constexpr size_t HOUT = (size_t)BATCH * DIM;            // h_final elems
constexpr size_t TRACE = (size_t)NLAYERS * BATCH * 3;   // per-trace elems
constexpr size_t OFF_ALIGN = HOUT;
constexpr size_t OFF_DIV   = HOUT + TRACE;
constexpr size_t OFF_TENS  = HOUT + 2 * TRACE;

// g_gram: [rn0, rn1, rn2, G00, G11, G22, G01, G02, G12]  (rn = 1/|anchor|)
__device__ float g_gram[12];

__device__ __forceinline__ float frcp(float x) { return __builtin_amdgcn_rcpf(x); }
__device__ __forceinline__ float frsq(float x) { return __builtin_amdgcn_rsqf(x); }
__device__ __forceinline__ float fsq(float x)  { return __builtin_amdgcn_sqrtf(x); }

__device__ __forceinline__ float wave_red(float v) {   // lane-0 sum (setup only)
#pragma unroll
  for (int off = 32; off > 0; off >>= 1) v += __shfl_down(v, off, 64);
  return v;
}

__device__ __forceinline__ float wave_allred(float v) { // all lanes get sum
#pragma unroll
  for (int off = 32; off > 0; off >>= 1) v += __shfl_xor(v, off, 64);
  return v;
}

// ---- setup: anchor Gram / inverse norms (1 block; precise math, cold) ----
__global__ __launch_bounds__(GTPB) void gram_kernel(
    const float* __restrict__ an0, const float* __restrict__ an1,
    const float* __restrict__ an2) {
  const int tid = threadIdx.x;
  float r[6];
#pragma unroll
  for (int i = 0; i < 6; ++i) r[i] = 0.f;
#pragma unroll
  for (int j = 0; j < DIM / (GTPB * 4); ++j) {
    const int idx = (tid + j * GTPB) * 4;
    const float4 x = *(const float4*)(an0 + idx);
    const float4 y = *(const float4*)(an1 + idx);
    const float4 z = *(const float4*)(an2 + idx);
    r[0] += x.x*x.x + x.y*x.y + x.z*x.z + x.w*x.w;
    r[1] += y.x*y.x + y.y*y.y + y.z*y.z + y.w*y.w;
    r[2] += z.x*z.x + z.y*z.y + z.z*z.z + z.w*z.w;
    r[3] += x.x*y.x + x.y*y.y + x.z*y.z + x.w*y.w;
    r[4] += x.x*z.x + x.y*z.y + x.z*z.z + x.w*z.w;
    r[5] += y.x*z.x + y.y*z.y + y.z*z.z + y.w*z.w;
  }
  __shared__ float lds[4][6];
  const int lane = tid & 63, wv = tid >> 6;
#pragma unroll
  for (int i = 0; i < 6; ++i) r[i] = wave_red(r[i]);
  if (lane == 0) {
#pragma unroll
    for (int i = 0; i < 6; ++i) lds[wv][i] = r[i];
  }
  __syncthreads();
  if (tid == 0) {
#pragma unroll
    for (int i = 0; i < 6; ++i)
      r[i] = lds[0][i] + lds[1][i] + lds[2][i] + lds[3][i];
    const float n0 = fmaxf(sqrtf(r[0]), 1e-12f);
    const float n1 = fmaxf(sqrtf(r[1]), 1e-12f);
    const float n2 = fmaxf(sqrtf(r[2]), 1e-12f);
    g_gram[0] = 1.f / n0;
    g_gram[1] = 1.f / n1;
    g_gram[2] = 1.f / n2;
    g_gram[3] = r[0] / (n0 * n0);
    g_gram[4] = r[1] / (n1 * n1);
    g_gram[5] = r[2] / (n2 * n2);
    g_gram[6] = r[3] / (n0 * n1);
    g_gram[7] = r[4] / (n0 * n2);
    g_gram[8] = r[5] / (n1 * n2);
  }
}

__global__ __launch_bounds__(TPB) void fused_kernel(
    const float* __restrict__ h0,
    const float* __restrict__ an0, const float* __restrict__ an1,
    const float* __restrict__ an2, float* __restrict__ out) {
  const int tid = threadIdx.x;
  const int lane = tid & 63;
  const int wv = tid >> 6;
  const int b = blockIdx.x * WPB + wv;            // this wave's row

  // ---- stage anchors into LDS (48KB), once per block ----
  __shared__ float sa0[DIM], sa1[DIM], sa2[DIM];
#pragma unroll
  for (int j = 0; j < DIM / (TPB * 4); ++j) {     // 2 float4 per thread/anchor
    const int idx = (tid + j * TPB) * 4;
    *(float4*)(sa0 + idx) = *(const float4*)(an0 + idx);
    *(float4*)(sa1 + idx) = *(const float4*)(an1 + idx);
    *(float4*)(sa2 + idx) = *(const float4*)(an2 + idx);
  }
  __syncthreads();  // only barrier; LDS is read-only below, waves drift free

  // ---- pass 1: whole row into 64 VGPRs; 4 dot accumulators ----
  const float* hrow = h0 + (size_t)b * DIM;
  float4 hv[FPW];
  float r0 = 0.f, r1 = 0.f, r2 = 0.f, r3 = 0.f;
#pragma unroll
  for (int j = 0; j < FPW; ++j) {
    const int idx = (j * 64 + lane) * 4;          // coalesced per wave
    hv[j] = *(const float4*)(hrow + idx);
    const float4 x = *(const float4*)(sa0 + idx);
    const float4 y = *(const float4*)(sa1 + idx);
    const float4 z = *(const float4*)(sa2 + idx);
    const float4 h = hv[j];
    r0 += h.x*h.x + h.y*h.y + h.z*h.z + h.w*h.w;
    r1 += h.x*x.x + h.y*x.y + h.z*x.z + h.w*x.w;
    r2 += h.x*y.x + h.y*y.y + h.z*y.z + h.w*y.w;
    r3 += h.x*z.x + h.y*z.y + h.z*z.z + h.w*z.w;
  }

  // ---- wave-local butterfly reduce: all lanes hold the sums; no LDS ----
  float s  = wave_allred(r0);
  float d0 = wave_allred(r1);
  float d1 = wave_allred(r2);
  float d2 = wave_allred(r3);

  const float rn0 = g_gram[0], rn1 = g_gram[1], rn2 = g_gram[2];
  const float G00 = g_gram[3], G11 = g_gram[4], G22 = g_gram[5];
  const float G01 = g_gram[6], G02 = g_gram[7], G12 = g_gram[8];
  d0 *= rn0; d1 *= rn1; d2 *= rn2;

  float A = 1.f, B0 = 0.f, B1 = 0.f, B2 = 0.f;
  float* tr_al = out + OFF_ALIGN + (size_t)b * 3;
  float* tr_dv = out + OFF_DIV   + (size_t)b * 3;
  float* tr_tn = out + OFF_TENS  + (size_t)b * 3;

  // ---- recurrence: redundant per-lane; division-free native math ----
#pragma unroll
  for (int l = 0; l < NLAYERS; ++l) {
    const float rhn = frsq(fmaxf(s, 1e-24f));
    const float al0 = d0 * rhn, al1 = d1 * rhn, al2 = d2 * rhn;
    const float dv0 = 1.f - al0, dv1 = 1.f - al1, dv2 = 1.f - al2;
    const float rr0 = frsq(fmaxf(s - 2.f*d0 + G00, 1e-24f));
    const float rr1 = frsq(fmaxf(s - 2.f*d1 + G11, 1e-24f));
    const float rr2 = frsq(fmaxf(s - 2.f*d2 + G22, 1e-24f));
    const float c0 = 0.10f * dv0 * rr0;
    const float c1 = 0.10f * dv1 * rr1;
    const float c2 = 0.05f * dv2 * rr2;
    if (lane == 0) {
      const size_t o = (size_t)l * (BATCH * 3);
      tr_al[o+0] = al0; tr_al[o+1] = al1; tr_al[o+2] = al2;
      tr_dv[o+0] = dv0; tr_dv[o+1] = dv1; tr_dv[o+2] = dv2;
      tr_tn[o+0] = fmaxf(dv0, 0.f); tr_tn[o+1] = fmaxf(dv1, 0.f);
      tr_tn[o+2] = fmaxf(dv2, 0.f);
    }
    const float a = 1.f - (c0 + c1 + c2);
    const float dn0 = a*d0 + c0*G00 + c1*G01 + c2*G02;
    const float dn1 = a*d1 + c0*G01 + c1*G11 + c2*G12;
    const float dn2 = a*d2 + c0*G02 + c1*G12 + c2*G22;
    float sn = a*a*s + 2.f*a*(c0*d0 + c1*d1 + c2*d2)
             + c0*c0*G00 + c1*c1*G11 + c2*c2*G22
             + 2.f*(c0*c1*G01 + c0*c2*G02 + c1*c2*G12);
    A = a * A;
    B0 = a*B0 + c0; B1 = a*B1 + c1; B2 = a*B2 + c2;
    s = sn; d0 = dn0; d1 = dn1; d2 = dn2;
    const float hn2 = fsq(s);
    if (hn2 > 10.0f) {                              // wave-uniform branch
      const float sc = 10.0f * frcp(hn2 + 1e-8f);
      A *= sc; B0 *= sc; B1 *= sc; B2 *= sc;
      d0 *= sc; d1 *= sc; d2 *= sc;
      s *= sc * sc;
    }
  }
  const float w0 = B0 * rn0, w1 = B1 * rn1, w2 = B2 * rn2;

  // ---- pass 2: h from registers; anchors from LDS ----
  float* orow = out + (size_t)b * DIM;
#pragma unroll
  for (int j = 0; j < FPW; ++j) {
    const int idx = (j * 64 + lane) * 4;
    const float4 x = *(const float4*)(sa0 + idx);
    const float4 y = *(const float4*)(sa1 + idx);
    const float4 z = *(const float4*)(sa2 + idx);
    const float4 h = hv[j];
    float4 o;
    o.x = A * h.x + w0 * x.x + w1 * y.x + w2 * z.x;
    o.y = A * h.y + w0 * x.y + w1 * y.y + w2 * z.y;
    o.z = A * h.z + w0 * x.z + w1 * y.z + w2 * z.z;
    o.w = A * h.w + w0 * x.w + w1 * y.w + w2 * z.w;
    *(float4*)(orow + idx) = o;
  }
}

extern "C" void kernel_launch(void* const* d_in, const int* in_sizes, int n_in,
                              void* d_out, int out_size, void* d_ws, size_t ws_size,
                              hipStream_t stream) {
  const float* h0  = (const float*)d_in[0];
  const float* an0 = (const float*)d_in[1];
  const float* an1 = (const float*)d_in[2];
  const float* an2 = (const float*)d_in[3];
  float* out = (float*)d_out;
  (void)d_ws; (void)ws_size;
  gram_kernel<<<1, GTPB, 0, stream>>>(an0, an1, an2);
  fused_kernel<<<GRID, TPB, 0, stream>>>(h0, an0, an1, an2, out);
}